// Round 1
// baseline (1100.515 us; speedup 1.0000x reference)
//
#include <hip/hip_runtime.h>
#include <math.h>

#define B_ 64
#define I_ 2048
#define K_ 16
#define N_ 32
#define D_ 32
#define P_ 64   // i-slices for sweep kernel

// ws layout (float offsets)
#define OFF_INT   0u           // inputsT [I][K][B]   2097152
#define OFF_CT    2097152u     // cT      [N][I][B]   4194304
#define OFF_BT    6291456u     // bT      [N][I][B]   4194304
#define OFF_SPART 10485760u    // spart   [N][P][B][D] 4194304
#define OFF_OUTT  14680064u    // outT    [N][D][B]   65536
// total 14745600 floats = 56.25 MB

// ---------------- transpose inputs[b][i][k] -> inT[i][k][b] ----------------
__global__ __launch_bounds__(256) void k_transpose(const float* __restrict__ in,
                                                   float* __restrict__ inT) {
    __shared__ float lds[B_][K_ + 1];
    const int i = blockIdx.x;
    const int t = threadIdx.x;
    const int b = t >> 2, kq = t & 3;
    const float4 v = *(const float4*)(in + ((size_t)b * I_ + i) * K_ + kq * 4);
    lds[b][kq * 4 + 0] = v.x; lds[b][kq * 4 + 1] = v.y;
    lds[b][kq * 4 + 2] = v.z; lds[b][kq * 4 + 3] = v.w;
    __syncthreads();
#pragma unroll
    for (int q = 0; q < 4; ++q) {
        const int j = t + q * 256;          // j = k*64 + b
        const int k = j >> 6, bb = j & 63;
        inT[(size_t)i * (K_ * B_) + j] = lds[bb][k];
    }
}

// ---------------- s-sweep: spart[n][p][b][d] = sum_{i in slice} c * u_hat ----------------
template<int UNIFORM>
__global__ __launch_bounds__(256) void k_sweep(const float* __restrict__ W,
                                               const float* __restrict__ inT,
                                               const float* __restrict__ cT,
                                               float* __restrict__ spart) {
    const int n = blockIdx.y;
    const int p = blockIdx.x;
    const int w = threadIdx.x >> 6;
    const int lane = threadIdx.x & 63;      // lane = b

    float acc[D_];
#pragma unroll
    for (int d = 0; d < D_; ++d) acc[d] = 0.f;

    const int ibase = p * 32 + w * 8;
    for (int q = 0; q < 8; ++q) {
        const int i = ibase + q;
        const int iu = __builtin_amdgcn_readfirstlane(i);
        const float c = UNIFORM ? (1.0f / N_)
                                : cT[((size_t)n * I_ + i) * B_ + lane];
        const float* xp = inT + (size_t)i * (K_ * B_) + lane;
        float xc[K_];
#pragma unroll
        for (int k = 0; k < K_; ++k) xc[k] = c * xp[k * B_];
        const float* wp = W + ((size_t)n * I_ + iu) * (D_ * K_);
#pragma unroll
        for (int d = 0; d < D_; ++d) {
            const float4* w4 = (const float4*)(wp + d * K_);
            const float4 w0 = w4[0], w1 = w4[1], w2 = w4[2], w3 = w4[3];
            float u = acc[d];
            u += xc[0] * w0.x + xc[1] * w0.y + xc[2] * w0.z + xc[3] * w0.w;
            u += xc[4] * w1.x + xc[5] * w1.y + xc[6] * w1.z + xc[7] * w1.w;
            u += xc[8] * w2.x + xc[9] * w2.y + xc[10] * w2.z + xc[11] * w2.w;
            u += xc[12] * w3.x + xc[13] * w3.y + xc[14] * w3.z + xc[15] * w3.w;
            acc[d] = u;
        }
    }

    // cross-wave reduce (4 waves) in LDS, then one write per block
    __shared__ float red[4][B_][D_ + 1];
#pragma unroll
    for (int d = 0; d < D_; ++d) red[w][lane][d] = acc[d];
    __syncthreads();
    const int t = threadIdx.x;
#pragma unroll
    for (int q = 0; q < 8; ++q) {
        const int j = t + q * 256;          // j = b*32 + d
        const int b = j >> 5, d = j & 31;
        const float s = red[0][b][d] + red[1][b][d] + red[2][b][d] + red[3][b][d];
        spart[((size_t)n * P_ + p) * (B_ * D_) + j] = s;
    }
}

// ---------------- reduce partials + squash ----------------
template<int FINAL>
__global__ __launch_bounds__(256) void k_reduce(const float* __restrict__ spart,
                                                float* __restrict__ outT,
                                                float* __restrict__ out) {
    const int gt = blockIdx.x * 256 + threadIdx.x;   // 65536 threads = N*B*D
    const int n = gt >> 11;
    const int rem = gt & 2047;                        // b*32 + d
    const int b = rem >> 5, d = rem & 31;
    const float* sp = spart + (size_t)n * (P_ * B_ * D_) + rem;
    float s = 0.f;
#pragma unroll 8
    for (int p = 0; p < P_; ++p) s += sp[p * (B_ * D_)];

    // sum of squares over d (32 consecutive lanes share (n,b))
    float sq = s * s;
#pragma unroll
    for (int off = 16; off >= 1; off >>= 1) sq += __shfl_xor(sq, off, 64);
    const float scale = sq / ((1.0f + sq) * sqrtf(sq + 1e-7f));
    const float o = scale * s;
    if (FINAL) {
        out[((size_t)b * N_ + n) * D_ + d] = o;       // [B][N][D]
    } else {
        outT[((size_t)n * D_ + d) * B_ + b] = o;      // [N][D][B]
    }
}

// ---------------- b-update + softmax over n -> cT ----------------
template<int FIRST>
__global__ __launch_bounds__(256) void k_update(const float* __restrict__ W,
                                                const float* __restrict__ inT,
                                                const float* __restrict__ outT,
                                                float* __restrict__ bT,
                                                float* __restrict__ cT) {
    const int w = threadIdx.x >> 6;
    const int lane = threadIdx.x & 63;     // lane = b
    const int i = blockIdx.x * 4 + w;
    const int iu = __builtin_amdgcn_readfirstlane(i);

    float x[K_];
    const float* xp = inT + (size_t)i * (K_ * B_) + lane;
#pragma unroll
    for (int k = 0; k < K_; ++k) x[k] = xp[k * B_];

    float bn[N_];
    for (int n = 0; n < N_; ++n) {
        float acc = FIRST ? 0.f : bT[((size_t)n * I_ + i) * B_ + lane];
        const float* wp = W + ((size_t)n * I_ + iu) * (D_ * K_);
        const float* op = outT + (size_t)n * (D_ * B_) + lane;
#pragma unroll
        for (int d = 0; d < D_; ++d) {
            const float4* w4 = (const float4*)(wp + d * K_);
            const float4 w0 = w4[0], w1 = w4[1], w2 = w4[2], w3 = w4[3];
            float u;
            u  = x[0] * w0.x + x[1] * w0.y + x[2] * w0.z + x[3] * w0.w;
            u += x[4] * w1.x + x[5] * w1.y + x[6] * w1.z + x[7] * w1.w;
            u += x[8] * w2.x + x[9] * w2.y + x[10] * w2.z + x[11] * w2.w;
            u += x[12] * w3.x + x[13] * w3.y + x[14] * w3.z + x[15] * w3.w;
            acc += op[d * B_] * u;
        }
        bn[n] = acc;
        if (FIRST) bT[((size_t)n * I_ + i) * B_ + lane] = acc;
    }
    // softmax over n (in registers)
    float m = bn[0];
#pragma unroll
    for (int n = 1; n < N_; ++n) m = fmaxf(m, bn[n]);
    float sum = 0.f;
#pragma unroll
    for (int n = 0; n < N_; ++n) { bn[n] = __expf(bn[n] - m); sum += bn[n]; }
    const float inv = 1.0f / sum;
#pragma unroll
    for (int n = 0; n < N_; ++n)
        cT[((size_t)n * I_ + i) * B_ + lane] = bn[n] * inv;
}

extern "C" void kernel_launch(void* const* d_in, const int* in_sizes, int n_in,
                              void* d_out, int out_size, void* d_ws, size_t ws_size,
                              hipStream_t stream) {
    const float* inputs = (const float*)d_in[0];
    const float* W      = (const float*)d_in[1];
    float* out = (float*)d_out;
    float* ws  = (float*)d_ws;
    float* inT   = ws + OFF_INT;
    float* cT    = ws + OFF_CT;
    float* bT    = ws + OFF_BT;
    float* spart = ws + OFF_SPART;
    float* outT  = ws + OFF_OUTT;

    k_transpose<<<I_, 256, 0, stream>>>(inputs, inT);
    // r = 0 (c uniform = 1/N since b=0)
    k_sweep<1><<<dim3(P_, N_), 256, 0, stream>>>(W, inT, cT, spart);
    k_reduce<0><<<256, 256, 0, stream>>>(spart, outT, out);
    k_update<1><<<I_ / 4, 256, 0, stream>>>(W, inT, outT, bT, cT);
    // r = 1
    k_sweep<0><<<dim3(P_, N_), 256, 0, stream>>>(W, inT, cT, spart);
    k_reduce<0><<<256, 256, 0, stream>>>(spart, outT, out);
    k_update<0><<<I_ / 4, 256, 0, stream>>>(W, inT, outT, bT, cT);
    // r = 2
    k_sweep<0><<<dim3(P_, N_), 256, 0, stream>>>(W, inT, cT, spart);
    k_reduce<1><<<256, 256, 0, stream>>>(spart, outT, out);
}